// Round 8
// baseline (783.975 us; speedup 1.0000x reference)
//
#include <hip/hip_runtime.h>
#include <math.h>

#define F_IN 128
#define F_HID 16
#define F_OUT 8
#define BSHIFT 7
#define BNODES 128   // nodes per bucket = 1<<BSHIFT
#define MAXNB 1024   // LDS arrays sized for nb <= 1024 (nb = 782)
#define CHUNK 8192   // edges per block in k_bucket

// bf16 helpers: round-to-nearest-even pack, cheap unpack
__device__ inline unsigned bf16rn(float x) {
    unsigned u = __float_as_uint(x);
    u += 0x7fffu + ((u >> 16) & 1u);
    return u >> 16;
}
__device__ inline float b2f(unsigned h) { return __uint_as_float(h << 16); }

// ---------------- zero bucket counters ----------------

__global__ void k_zero(int* __restrict__ p, int m) {
    int i = blockIdx.x * blockDim.x + threadIdx.x;
    if (i < m) p[i] = 0;
}

// ---------------- bucket histogram (LDS-aggregated) ----------------

__global__ __launch_bounds__(256) void k_hist(const int* __restrict__ dst,
                                              int* __restrict__ bucket_cnt,
                                              int e, int nb) {
    __shared__ int sh[MAXNB];
    int t = threadIdx.x;
    for (int i = t; i < nb; i += 256) sh[i] = 0;
    __syncthreads();
    int stride = gridDim.x * 256;
    for (int i = blockIdx.x * 256 + t; i < e; i += stride)
        atomicAdd(&sh[dst[i] >> BSHIFT], 1);
    __syncthreads();
    for (int i = t; i < nb; i += 256)
        if (sh[i]) atomicAdd(&bucket_cnt[i], sh[i]);
}

// ---------------- exclusive scan of bucket counts (nb <= 1024, 1 block) ----------------

__global__ __launch_bounds__(256) void k_scan(const int* __restrict__ bucket_cnt,
                                              int* __restrict__ base,
                                              int* __restrict__ cursor, int nb, int e) {
    __shared__ int sh[256];
    int t = threadIdx.x;
    int v[4], s = 0;
#pragma unroll
    for (int q = 0; q < 4; ++q) {
        int i = t * 4 + q;
        v[q] = (i < nb) ? bucket_cnt[i] : 0;
        s += v[q];
    }
    sh[t] = s;
    __syncthreads();
    for (int off = 1; off < 256; off <<= 1) {
        int x = (t >= off) ? sh[t - off] : 0;
        __syncthreads();
        sh[t] += x;
        __syncthreads();
    }
    int run = (t > 0) ? sh[t - 1] : 0;
#pragma unroll
    for (int q = 0; q < 4; ++q) {
        int i = t * 4 + q;
        if (i < nb) { base[i] = run; cursor[i] = run; }
        run += v[q];
    }
    if (t == 0) base[nb] = e;
}

// ---------------- rank-then-write bucket scatter (packed 4B edges) ----------------

__global__ __launch_bounds__(1024) void k_bucket(const int* __restrict__ src,
                                                 const int* __restrict__ dst,
                                                 int* __restrict__ cursor,
                                                 int* __restrict__ ebuf, int e, int nb) {
    __shared__ int hist[MAXNB];
    __shared__ int ofs[MAXNB];
    int t = threadIdx.x;
    int beg = blockIdx.x * CHUNK;
    int end = min(beg + CHUNK, e);
    for (int i = t; i < nb; i += 1024) hist[i] = 0;
    __syncthreads();
    for (int i = beg + t; i < end; i += 1024)
        atomicAdd(&hist[dst[i] >> BSHIFT], 1);
    __syncthreads();
    for (int i = t; i < nb; i += 1024)
        ofs[i] = hist[i] ? atomicAdd(&cursor[i], hist[i]) : 0;
    __syncthreads();
    for (int i = beg + t; i < end; i += 1024) {
        int s = src[i], d = dst[i];
        int pos = atomicAdd(&ofs[d >> BSHIFT], 1);
        ebuf[pos] = (s << BSHIFT) | (d & (BNODES - 1));
    }
}

// ---------------- per-bucket degree count -> dinv (no global atomics) ----------------

__global__ __launch_bounds__(256) void k_degdinv(const int* __restrict__ ebuf,
                                                 const int* __restrict__ base,
                                                 float* __restrict__ dinv, int n) {
    __shared__ int cnt[BNODES];
    int b = blockIdx.x, t = threadIdx.x;
    if (t < BNODES) cnt[t] = 0;
    __syncthreads();
    int st = base[b], en = base[b + 1];
    for (int i = st + t; i < en; i += 256)
        atomicAdd(&cnt[ebuf[i] & (BNODES - 1)], 1);
    __syncthreads();
    int node = b * BNODES + t;
    if (t < BNODES && node < n) dinv[node] = rsqrtf((float)cnt[t] + 1.0f);
}

// ---------------- layer 1 GEMM: g1b = bf16( dinv * (x @ W1) ) ----------------
// 16 rows x 16 cols; pairwise pack via shfl_xor, even-c lanes store uint.

__global__ __launch_bounds__(256) void k_gemm1(const float* __restrict__ x,
                                               const float* __restrict__ W1,
                                               const float* __restrict__ dinv,
                                               unsigned short* __restrict__ g1b, int n) {
    __shared__ float Ws[F_IN][F_HID];
    __shared__ float xs[16][F_IN + 1];
    int t = threadIdx.x;
    for (int i = t; i < F_IN * F_HID; i += 256) Ws[i / F_HID][i % F_HID] = W1[i];
    int row0 = blockIdx.x * 16;
    for (int i = t; i < 16 * F_IN; i += 256) {
        int r = i >> 7, c = i & 127;
        int gr = row0 + r;
        xs[r][c] = (gr < n) ? x[(long long)gr * F_IN + c] : 0.0f;
    }
    __syncthreads();
    int r = t >> 4, c = t & 15;
    float acc = 0.0f;
#pragma unroll
    for (int k = 0; k < F_IN; ++k) acc = fmaf(xs[r][k], Ws[k][c], acc);
    int gr = row0 + r;
    acc *= (gr < n) ? dinv[gr] : 0.0f;
    float partner = __shfl_xor(acc, 1);  // t^1 flips bit0 of c
    if (gr < n && !(c & 1)) {
        unsigned lo = bf16rn(acc), hi = bf16rn(partner);
        ((unsigned*)g1b)[(size_t)gr * 8 + (c >> 1)] = lo | (hi << 16);
    }
}

// ---------------- layer 1 gather: bf16 rows, LDS fp32 tile, fused bias+relu ----------------
// 1024 threads, 2 lanes per edge (16B uint4 per lane) -> 32 edges/wave in flight.

__global__ __launch_bounds__(1024) void k_gather1(const int* __restrict__ ebuf,
                                                  const int* __restrict__ base,
                                                  const float* __restrict__ dinv,
                                                  const unsigned short* __restrict__ g1b,
                                                  const float* __restrict__ b1,
                                                  float* __restrict__ out1, int n) {
    __shared__ float tile[BNODES][F_HID + 1];
    int b = blockIdx.x, t = threadIdx.x;
    for (int i = t; i < BNODES * (F_HID + 1); i += 1024) ((float*)tile)[i] = 0.0f;
    __syncthreads();
    int st = base[b], en = base[b + 1];
    int g = t >> 1, q = t & 1;
    int i = st + g;
    int ep = (i < en) ? ebuf[i] : 0;
    while (i < en) {
        int inext = i + 512;
        int epn = (inext < en) ? ebuf[inext] : 0;
        int s = ep >> BSHIFT, r = ep & (BNODES - 1);
        const uint4 v = *(const uint4*)&g1b[(size_t)s * F_HID + q * 8];
        float* tp = &tile[r][q * 8];
        atomicAdd(tp + 0, b2f(v.x & 0xffffu));
        atomicAdd(tp + 1, b2f(v.x >> 16));
        atomicAdd(tp + 2, b2f(v.y & 0xffffu));
        atomicAdd(tp + 3, b2f(v.y >> 16));
        atomicAdd(tp + 4, b2f(v.z & 0xffffu));
        atomicAdd(tp + 5, b2f(v.z >> 16));
        atomicAdd(tp + 6, b2f(v.w & 0xffffu));
        atomicAdd(tp + 7, b2f(v.w >> 16));
        ep = epn;
        i = inext;
    }
    __syncthreads();
    int f = t & 15;
#pragma unroll
    for (int p = 0; p < 2; ++p) {
        int r = p * 64 + (t >> 4);
        int node = b * BNODES + r;
        if (node < n) {
            float self = b2f((unsigned)g1b[(size_t)node * F_HID + f]);
            float v = tile[r][f] + self;  // + self-loop
            out1[(size_t)node * F_HID + f] = fmaxf(dinv[node] * v + b1[f], 0.0f);
        }
    }
}

// ---------------- layer 2 GEMM: g2 = dinv * (out1 @ W2) (fp32) ----------------

__global__ __launch_bounds__(256) void k_gemm2(const float* __restrict__ out1,
                                               const float* __restrict__ W2,
                                               const float* __restrict__ dinv,
                                               float* __restrict__ g2, int n) {
    __shared__ float Ws[F_HID][F_OUT];
    int t = threadIdx.x;
    if (t < F_HID * F_OUT) Ws[t / F_OUT][t % F_OUT] = W2[t];
    __syncthreads();
    int i = blockIdx.x * blockDim.x + t;
    if (i >= n) return;
    const float4* p = (const float4*)(&out1[i * F_HID]);
    float r[F_HID];
#pragma unroll
    for (int q = 0; q < 4; ++q) {
        float4 v = p[q];
        r[q * 4 + 0] = v.x; r[q * 4 + 1] = v.y; r[q * 4 + 2] = v.z; r[q * 4 + 3] = v.w;
    }
    float di = dinv[i];
    float o[F_OUT];
#pragma unroll
    for (int j = 0; j < F_OUT; ++j) {
        float acc = 0.0f;
#pragma unroll
        for (int kk = 0; kk < F_HID; ++kk) acc = fmaf(r[kk], Ws[kk][j], acc);
        o[j] = acc * di;
    }
    float4* q4 = (float4*)(&g2[i * F_OUT]);
    q4[0] = make_float4(o[0], o[1], o[2], o[3]);
    q4[1] = make_float4(o[4], o[5], o[6], o[7]);
}

// ---------------- layer 2 gather: LDS tile + fused bias + log_softmax ----------------
// 1024 threads, 2 lanes per edge (fp32 g2 is 3.2 MB, L2-resident already).

__global__ __launch_bounds__(1024) void k_gather2(const int* __restrict__ ebuf,
                                                  const int* __restrict__ base,
                                                  const float* __restrict__ dinv,
                                                  const float* __restrict__ g2,
                                                  const float* __restrict__ b2,
                                                  float* __restrict__ out, int n) {
    __shared__ float tile[BNODES][F_OUT + 1];
    int b = blockIdx.x, t = threadIdx.x;
    for (int i = t; i < BNODES * (F_OUT + 1); i += 1024) ((float*)tile)[i] = 0.0f;
    __syncthreads();
    int st = base[b], en = base[b + 1];
    int g = t >> 1, q = t & 1;
    int i = st + g;
    int ep = (i < en) ? ebuf[i] : 0;
    while (i < en) {
        int inext = i + 512;
        int epn = (inext < en) ? ebuf[inext] : 0;
        int s = ep >> BSHIFT, r = ep & (BNODES - 1);
        const float4 v = *(const float4*)&g2[(size_t)s * F_OUT + q * 4];
        float* tp = &tile[r][q * 4];
        atomicAdd(tp + 0, v.x);
        atomicAdd(tp + 1, v.y);
        atomicAdd(tp + 2, v.z);
        atomicAdd(tp + 3, v.w);
        ep = epn;
        i = inext;
    }
    __syncthreads();
    int f = t & 7;
    int r = t >> 3;  // 0..127, exactly one pass
    int node = b * BNODES + r;
    if (node < n) {
        float v = dinv[node] * (tile[r][f] + g2[(size_t)node * F_OUT + f]) + b2[f];
        float m = v;
        m = fmaxf(m, __shfl_xor(m, 1));
        m = fmaxf(m, __shfl_xor(m, 2));
        m = fmaxf(m, __shfl_xor(m, 4));
        float ex = expf(v - m);
        float ss = ex;
        ss += __shfl_xor(ss, 1);
        ss += __shfl_xor(ss, 2);
        ss += __shfl_xor(ss, 4);
        out[(size_t)node * F_OUT + f] = v - m - logf(ss);
    }
}

// ---------------- launch ----------------

extern "C" void kernel_launch(void* const* d_in, const int* in_sizes, int n_in,
                              void* d_out, int out_size, void* d_ws, size_t ws_size,
                              hipStream_t stream) {
    const float* x  = (const float*)d_in[0];
    const int*   ei = (const int*)d_in[1];
    const float* W1 = (const float*)d_in[2];
    const float* b1 = (const float*)d_in[3];
    const float* W2 = (const float*)d_in[4];
    const float* b2 = (const float*)d_in[5];
    float* out = (float*)d_out;

    const int n = in_sizes[0] / F_IN;   // 100000
    const int e = in_sizes[1] / 2;      // 3200000
    const int* src = ei;
    const int* dst = ei + e;
    const int nb = (n + BNODES - 1) / BNODES;  // 782

    char* w = (char*)d_ws;
    float* dinv         = (float*)w; w += (size_t)n * 4;
    int* ebuf           = (int*)w;   w += (size_t)e * 4;
    int* bucket_cnt     = (int*)w;   w += (size_t)(nb + 4) * 4;
    int* base           = (int*)w;   w += (size_t)(nb + 4) * 4;
    int* cursor         = (int*)w;   w += (size_t)(nb + 4) * 4;
    w = (char*)(((size_t)w + 15) & ~(size_t)15);
    unsigned short* g1b = (unsigned short*)w; w += (size_t)n * F_HID * 2;
    w = (char*)(((size_t)w + 15) & ~(size_t)15);
    float* out1         = (float*)w; w += (size_t)n * F_HID * 4;
    float* g2           = (float*)w; w += (size_t)n * F_OUT * 4;

    k_zero<<<(nb + 255) / 256, 256, 0, stream>>>(bucket_cnt, nb);
    k_hist<<<256, 256, 0, stream>>>(dst, bucket_cnt, e, nb);
    k_scan<<<1, 256, 0, stream>>>(bucket_cnt, base, cursor, nb, e);
    k_bucket<<<(e + CHUNK - 1) / CHUNK, 1024, 0, stream>>>(src, dst, cursor, ebuf, e, nb);
    k_degdinv<<<nb, 256, 0, stream>>>(ebuf, base, dinv, n);
    k_gemm1<<<(n + 15) / 16, 256, 0, stream>>>(x, W1, dinv, g1b, n);
    k_gather1<<<nb, 1024, 0, stream>>>(ebuf, base, dinv, g1b, b1, out1, n);
    k_gemm2<<<(n + 255) / 256, 256, 0, stream>>>(out1, W2, dinv, g2, n);
    k_gather2<<<nb, 1024, 0, stream>>>(ebuf, base, dinv, g2, b2, out, n);
}

// Round 9
// 367.216 us; speedup vs baseline: 2.1349x; 2.1349x over previous
//
#include <hip/hip_runtime.h>
#include <math.h>

#define F_IN 128
#define F_HID 16
#define F_OUT 8
#define BSHIFT 7
#define BNODES 128   // nodes per bucket = 1<<BSHIFT
#define MAXNB 1024   // LDS arrays sized for nb <= 1024 (nb = 782)
#define CHUNK 8192   // edges per block in k_bucket

// bf16 helpers: round-to-nearest-even pack, cheap unpack
__device__ inline unsigned bf16rn(float x) {
    unsigned u = __float_as_uint(x);
    u += 0x7fffu + ((u >> 16) & 1u);
    return u >> 16;
}
__device__ inline float b2f(unsigned h) { return __uint_as_float(h << 16); }

// ---------------- zero bucket counters ----------------

__global__ void k_zero(int* __restrict__ p, int m) {
    int i = blockIdx.x * blockDim.x + threadIdx.x;
    if (i < m) p[i] = 0;
}

// ---------------- bucket histogram (LDS-aggregated) ----------------

__global__ __launch_bounds__(256) void k_hist(const int* __restrict__ dst,
                                              int* __restrict__ bucket_cnt,
                                              int e, int nb) {
    __shared__ int sh[MAXNB];
    int t = threadIdx.x;
    for (int i = t; i < nb; i += 256) sh[i] = 0;
    __syncthreads();
    int stride = gridDim.x * 256;
    for (int i = blockIdx.x * 256 + t; i < e; i += stride)
        atomicAdd(&sh[dst[i] >> BSHIFT], 1);
    __syncthreads();
    for (int i = t; i < nb; i += 256)
        if (sh[i]) atomicAdd(&bucket_cnt[i], sh[i]);
}

// ---------------- exclusive scan of bucket counts (nb <= 1024, 1 block) ----------------

__global__ __launch_bounds__(256) void k_scan(const int* __restrict__ bucket_cnt,
                                              int* __restrict__ base,
                                              int* __restrict__ cursor,
                                              int* __restrict__ row_ptr, int nb, int e, int n) {
    __shared__ int sh[256];
    int t = threadIdx.x;
    int v[4], s = 0;
#pragma unroll
    for (int q = 0; q < 4; ++q) {
        int i = t * 4 + q;
        v[q] = (i < nb) ? bucket_cnt[i] : 0;
        s += v[q];
    }
    sh[t] = s;
    __syncthreads();
    for (int off = 1; off < 256; off <<= 1) {
        int x = (t >= off) ? sh[t - off] : 0;
        __syncthreads();
        sh[t] += x;
        __syncthreads();
    }
    int run = (t > 0) ? sh[t - 1] : 0;
#pragma unroll
    for (int q = 0; q < 4; ++q) {
        int i = t * 4 + q;
        if (i < nb) { base[i] = run; cursor[i] = run; }
        run += v[q];
    }
    if (t == 0) { base[nb] = e; row_ptr[n] = e; }  // sentinels
}

// ---------------- rank-then-write bucket scatter (packed 4B edges) ----------------

__global__ __launch_bounds__(1024) void k_bucket(const int* __restrict__ src,
                                                 const int* __restrict__ dst,
                                                 int* __restrict__ cursor,
                                                 int* __restrict__ ebuf, int e, int nb) {
    __shared__ int hist[MAXNB];
    __shared__ int ofs[MAXNB];
    int t = threadIdx.x;
    int beg = blockIdx.x * CHUNK;
    int end = min(beg + CHUNK, e);
    for (int i = t; i < nb; i += 1024) hist[i] = 0;
    __syncthreads();
    for (int i = beg + t; i < end; i += 1024)
        atomicAdd(&hist[dst[i] >> BSHIFT], 1);
    __syncthreads();
    for (int i = t; i < nb; i += 1024)
        ofs[i] = hist[i] ? atomicAdd(&cursor[i], hist[i]) : 0;
    __syncthreads();
    for (int i = beg + t; i < end; i += 1024) {
        int s = src[i], d = dst[i];
        int pos = atomicAdd(&ofs[d >> BSHIFT], 1);
        ebuf[pos] = (s << BSHIFT) | (d & (BNODES - 1));
    }
}

// ---------------- per-bucket counting sort -> per-node CSR + row_ptr + dinv ----------------
// LDS int atomics only (cheap, cf. k_degdinv). Each block writes one contiguous
// ~16KB csr range -> full-line writebacks.

__global__ __launch_bounds__(256) void k_sort(const int* __restrict__ ebuf,
                                              const int* __restrict__ base,
                                              int* __restrict__ csr,
                                              int* __restrict__ row_ptr,
                                              float* __restrict__ dinv, int n) {
    __shared__ int cnt[BNODES];
    __shared__ int sh[BNODES];
    __shared__ int cur[BNODES];
    int b = blockIdx.x, t = threadIdx.x;
    if (t < BNODES) cnt[t] = 0;
    __syncthreads();
    int st = base[b], en = base[b + 1];
    for (int i = st + t; i < en; i += 256)
        atomicAdd(&cnt[ebuf[i] & (BNODES - 1)], 1);
    __syncthreads();
    if (t < BNODES) sh[t] = cnt[t];
    __syncthreads();
    for (int off = 1; off < BNODES; off <<= 1) {
        int x = (t >= off && t < BNODES) ? sh[t - off] : 0;
        __syncthreads();
        if (t < BNODES) sh[t] += x;
        __syncthreads();
    }
    if (t < BNODES) {
        int excl = (t > 0) ? sh[t - 1] : 0;
        int node = b * BNODES + t;
        if (node < n) {
            row_ptr[node] = st + excl;
            dinv[node] = rsqrtf((float)cnt[t] + 1.0f);
        }
        cur[t] = st + excl;
    }
    __syncthreads();
    for (int i = st + t; i < en; i += 256) {
        int ep = ebuf[i];
        int pos = atomicAdd(&cur[ep & (BNODES - 1)], 1);
        csr[pos] = ep >> BSHIFT;
    }
}

// ---------------- layer 1 GEMM: g1b = bf16( dinv * (x @ W1) ) ----------------

__global__ __launch_bounds__(256) void k_gemm1(const float* __restrict__ x,
                                               const float* __restrict__ W1,
                                               const float* __restrict__ dinv,
                                               unsigned short* __restrict__ g1b, int n) {
    __shared__ float Ws[F_IN][F_HID];
    __shared__ float xs[16][F_IN + 1];
    int t = threadIdx.x;
    for (int i = t; i < F_IN * F_HID; i += 256) Ws[i / F_HID][i % F_HID] = W1[i];
    int row0 = blockIdx.x * 16;
    for (int i = t; i < 16 * F_IN; i += 256) {
        int r = i >> 7, c = i & 127;
        int gr = row0 + r;
        xs[r][c] = (gr < n) ? x[(long long)gr * F_IN + c] : 0.0f;
    }
    __syncthreads();
    int r = t >> 4, c = t & 15;
    float acc = 0.0f;
#pragma unroll
    for (int k = 0; k < F_IN; ++k) acc = fmaf(xs[r][k], Ws[k][c], acc);
    int gr = row0 + r;
    acc *= (gr < n) ? dinv[gr] : 0.0f;
    float partner = __shfl_xor(acc, 1);  // t^1 flips bit0 of c
    if (gr < n && !(c & 1)) {
        unsigned lo = bf16rn(acc), hi = bf16rn(partner);
        ((unsigned*)g1b)[(size_t)gr * 8 + (c >> 1)] = lo | (hi << 16);
    }
}

// ---------------- layer 1 gather + relu + gemm2, NO atomics ----------------
// 2 lanes per node: register accumulation over CSR neighbor list (bf16 rows,
// L2-resident); pair exchanges hidden halves via shfl_xor; W2 applied inline.
// Writes g2 = dinv * (relu(...) @ W2) directly (out1 buffer eliminated).

__global__ __launch_bounds__(256) void k_gather1(const int* __restrict__ row_ptr,
                                                 const int* __restrict__ csr,
                                                 const float* __restrict__ dinv,
                                                 const unsigned short* __restrict__ g1b,
                                                 const float* __restrict__ b1,
                                                 const float* __restrict__ W2,
                                                 float* __restrict__ g2, int n) {
    int t = threadIdx.x;
    int node = blockIdx.x * 128 + (t >> 1);
    int q = t & 1;
    if (node >= n) return;
    int st = row_ptr[node], en = row_ptr[node + 1];
    const uint4* rows = (const uint4*)g1b;  // half-row q of node i at rows[i*2+q]
    float a[8];
    uint4 v = rows[(size_t)node * 2 + q];  // self-loop
    a[0] = b2f(v.x & 0xffffu); a[1] = b2f(v.x >> 16);
    a[2] = b2f(v.y & 0xffffu); a[3] = b2f(v.y >> 16);
    a[4] = b2f(v.z & 0xffffu); a[5] = b2f(v.z >> 16);
    a[6] = b2f(v.w & 0xffffu); a[7] = b2f(v.w >> 16);
    int k = st;
    for (; k + 2 <= en; k += 2) {
        int s0 = csr[k], s1 = csr[k + 1];
        uint4 v0 = rows[(size_t)s0 * 2 + q];
        uint4 v1 = rows[(size_t)s1 * 2 + q];
        a[0] += b2f(v0.x & 0xffffu) + b2f(v1.x & 0xffffu);
        a[1] += b2f(v0.x >> 16)     + b2f(v1.x >> 16);
        a[2] += b2f(v0.y & 0xffffu) + b2f(v1.y & 0xffffu);
        a[3] += b2f(v0.y >> 16)     + b2f(v1.y >> 16);
        a[4] += b2f(v0.z & 0xffffu) + b2f(v1.z & 0xffffu);
        a[5] += b2f(v0.z >> 16)     + b2f(v1.z >> 16);
        a[6] += b2f(v0.w & 0xffffu) + b2f(v1.w & 0xffffu);
        a[7] += b2f(v0.w >> 16)     + b2f(v1.w >> 16);
    }
    if (k < en) {
        int s0 = csr[k];
        uint4 v0 = rows[(size_t)s0 * 2 + q];
        a[0] += b2f(v0.x & 0xffffu); a[1] += b2f(v0.x >> 16);
        a[2] += b2f(v0.y & 0xffffu); a[3] += b2f(v0.y >> 16);
        a[4] += b2f(v0.z & 0xffffu); a[5] += b2f(v0.z >> 16);
        a[6] += b2f(v0.w & 0xffffu); a[7] += b2f(v0.w >> 16);
    }
    float di = dinv[node];
    float h_own[8], h_oth[8];
#pragma unroll
    for (int j = 0; j < 8; ++j)
        h_own[j] = fmaxf(di * a[j] + b1[q * 8 + j], 0.0f);
#pragma unroll
    for (int j = 0; j < 8; ++j) h_oth[j] = __shfl_xor(h_own[j], 1);
    float flo[8], fhi[8];
#pragma unroll
    for (int j = 0; j < 8; ++j) {
        flo[j] = (q == 0) ? h_own[j] : h_oth[j];  // features 0..7
        fhi[j] = (q == 0) ? h_oth[j] : h_own[j];  // features 8..15
    }
    int jj0 = q * 4;
    float o0 = 0, o1 = 0, o2 = 0, o3 = 0;
#pragma unroll
    for (int kk = 0; kk < 16; ++kk) {
        float hk = (kk < 8) ? flo[kk] : fhi[kk - 8];
        const float* wr = &W2[kk * F_OUT + jj0];
        o0 = fmaf(hk, wr[0], o0);
        o1 = fmaf(hk, wr[1], o1);
        o2 = fmaf(hk, wr[2], o2);
        o3 = fmaf(hk, wr[3], o3);
    }
    *(float4*)&g2[(size_t)node * F_OUT + jj0] =
        make_float4(o0 * di, o1 * di, o2 * di, o3 * di);
}

// ---------------- layer 2 gather + bias + log_softmax, NO atomics ----------------
// 2 lanes per node (float4 half-rows); pair-reduce via shfl_xor(1).

__global__ __launch_bounds__(256) void k_gather2(const int* __restrict__ row_ptr,
                                                 const int* __restrict__ csr,
                                                 const float* __restrict__ dinv,
                                                 const float* __restrict__ g2,
                                                 const float* __restrict__ b2,
                                                 float* __restrict__ out, int n) {
    int t = threadIdx.x;
    int node = blockIdx.x * 128 + (t >> 1);
    int q = t & 1;
    if (node >= n) return;
    int st = row_ptr[node], en = row_ptr[node + 1];
    const float4* rows = (const float4*)g2;  // half-row q of node i at rows[i*2+q]
    float4 s4 = rows[(size_t)node * 2 + q];  // self-loop
    float a0 = s4.x, a1 = s4.y, a2 = s4.z, a3 = s4.w;
    int k = st;
    for (; k + 2 <= en; k += 2) {
        int s0 = csr[k], s1 = csr[k + 1];
        float4 v0 = rows[(size_t)s0 * 2 + q];
        float4 v1 = rows[(size_t)s1 * 2 + q];
        a0 += v0.x + v1.x; a1 += v0.y + v1.y;
        a2 += v0.z + v1.z; a3 += v0.w + v1.w;
    }
    if (k < en) {
        float4 v0 = rows[(size_t)csr[k] * 2 + q];
        a0 += v0.x; a1 += v0.y; a2 += v0.z; a3 += v0.w;
    }
    float di = dinv[node];
    float v0 = di * a0 + b2[q * 4 + 0];
    float v1 = di * a1 + b2[q * 4 + 1];
    float v2 = di * a2 + b2[q * 4 + 2];
    float v3 = di * a3 + b2[q * 4 + 3];
    float m = fmaxf(fmaxf(v0, v1), fmaxf(v2, v3));
    m = fmaxf(m, __shfl_xor(m, 1));
    float ss = expf(v0 - m) + expf(v1 - m) + expf(v2 - m) + expf(v3 - m);
    ss += __shfl_xor(ss, 1);
    float ls = m + logf(ss);
    *(float4*)&out[(size_t)node * F_OUT + q * 4] =
        make_float4(v0 - ls, v1 - ls, v2 - ls, v3 - ls);
}

// ---------------- launch ----------------

extern "C" void kernel_launch(void* const* d_in, const int* in_sizes, int n_in,
                              void* d_out, int out_size, void* d_ws, size_t ws_size,
                              hipStream_t stream) {
    const float* x  = (const float*)d_in[0];
    const int*   ei = (const int*)d_in[1];
    const float* W1 = (const float*)d_in[2];
    const float* b1 = (const float*)d_in[3];
    const float* W2 = (const float*)d_in[4];
    const float* b2 = (const float*)d_in[5];
    float* out = (float*)d_out;

    const int n = in_sizes[0] / F_IN;   // 100000
    const int e = in_sizes[1] / 2;      // 3200000
    const int* src = ei;
    const int* dst = ei + e;
    const int nb = (n + BNODES - 1) / BNODES;  // 782

    char* w = (char*)d_ws;
    float* dinv         = (float*)w; w += (size_t)n * 4;
    int* ebuf           = (int*)w;   w += (size_t)e * 4;
    int* csr            = (int*)w;   w += (size_t)e * 4;
    int* row_ptr        = (int*)w;   w += (size_t)(n + 4) * 4;
    int* bucket_cnt     = (int*)w;   w += (size_t)(nb + 4) * 4;
    int* base           = (int*)w;   w += (size_t)(nb + 4) * 4;
    int* cursor         = (int*)w;   w += (size_t)(nb + 4) * 4;
    w = (char*)(((size_t)w + 15) & ~(size_t)15);
    unsigned short* g1b = (unsigned short*)w; w += (size_t)n * F_HID * 2;
    w = (char*)(((size_t)w + 15) & ~(size_t)15);
    float* g2           = (float*)w; w += (size_t)n * F_OUT * 4;

    k_zero<<<(nb + 255) / 256, 256, 0, stream>>>(bucket_cnt, nb);
    k_hist<<<256, 256, 0, stream>>>(dst, bucket_cnt, e, nb);
    k_scan<<<1, 256, 0, stream>>>(bucket_cnt, base, cursor, row_ptr, nb, e, n);
    k_bucket<<<(e + CHUNK - 1) / CHUNK, 1024, 0, stream>>>(src, dst, cursor, ebuf, e, nb);
    k_sort<<<nb, 256, 0, stream>>>(ebuf, base, csr, row_ptr, dinv, n);
    k_gemm1<<<(n + 15) / 16, 256, 0, stream>>>(x, W1, dinv, g1b, n);
    k_gather1<<<(n + 127) / 128, 256, 0, stream>>>(row_ptr, csr, dinv, g1b, b1, W2, g2, n);
    k_gather2<<<(n + 127) / 128, 256, 0, stream>>>(row_ptr, csr, dinv, g2, b2, out, n);
}

// Round 12
// 278.873 us; speedup vs baseline: 2.8112x; 1.3168x over previous
//
#include <hip/hip_runtime.h>
#include <math.h>

#define F_IN 128
#define F_HID 16
#define F_OUT 8
#define BSHIFT 7
#define BNODES 128   // nodes per bucket = 1<<BSHIFT
#define MAXNB 1024   // LDS arrays sized for nb <= 1024 (nb = 782)
#define CHUNK 8192   // edges per block in k_bucket

// bf16 helpers: round-to-nearest-even pack, cheap unpack
__device__ inline unsigned bf16rn(float x) {
    unsigned u = __float_as_uint(x);
    u += 0x7fffu + ((u >> 16) & 1u);
    return u >> 16;
}
__device__ inline float b2f(unsigned h) { return __uint_as_float(h << 16); }

// ---------------- zero bucket counters ----------------

__global__ void k_zero(int* __restrict__ p, int m) {
    int i = blockIdx.x * blockDim.x + threadIdx.x;
    if (i < m) p[i] = 0;
}

// ---------------- bucket histogram (LDS-aggregated) ----------------

__global__ __launch_bounds__(256) void k_hist(const int* __restrict__ dst,
                                              int* __restrict__ bucket_cnt,
                                              int e, int nb) {
    __shared__ int sh[MAXNB];
    int t = threadIdx.x;
    for (int i = t; i < nb; i += 256) sh[i] = 0;
    __syncthreads();
    int stride = gridDim.x * 256;
    for (int i = blockIdx.x * 256 + t; i < e; i += stride)
        atomicAdd(&sh[dst[i] >> BSHIFT], 1);
    __syncthreads();
    for (int i = t; i < nb; i += 256)
        if (sh[i]) atomicAdd(&bucket_cnt[i], sh[i]);
}

// ---------------- exclusive scan of bucket counts (nb <= 1024, 1 block) ----------------

__global__ __launch_bounds__(256) void k_scan(const int* __restrict__ bucket_cnt,
                                              int* __restrict__ base,
                                              int* __restrict__ cursor,
                                              int* __restrict__ row_ptr, int nb, int e, int n) {
    __shared__ int sh[256];
    int t = threadIdx.x;
    int v[4], s = 0;
#pragma unroll
    for (int q = 0; q < 4; ++q) {
        int i = t * 4 + q;
        v[q] = (i < nb) ? bucket_cnt[i] : 0;
        s += v[q];
    }
    sh[t] = s;
    __syncthreads();
    for (int off = 1; off < 256; off <<= 1) {
        int x = (t >= off) ? sh[t - off] : 0;
        __syncthreads();
        sh[t] += x;
        __syncthreads();
    }
    int run = (t > 0) ? sh[t - 1] : 0;
#pragma unroll
    for (int q = 0; q < 4; ++q) {
        int i = t * 4 + q;
        if (i < nb) { base[i] = run; cursor[i] = run; }
        run += v[q];
    }
    if (t == 0) { base[nb] = e; row_ptr[n] = e; }  // sentinels
}

// ---------------- rank-then-write bucket scatter (packed 4B edges) ----------------

__global__ __launch_bounds__(1024) void k_bucket(const int* __restrict__ src,
                                                 const int* __restrict__ dst,
                                                 int* __restrict__ cursor,
                                                 int* __restrict__ ebuf, int e, int nb) {
    __shared__ int hist[MAXNB];
    __shared__ int ofs[MAXNB];
    int t = threadIdx.x;
    int beg = blockIdx.x * CHUNK;
    int end = min(beg + CHUNK, e);
    for (int i = t; i < nb; i += 1024) hist[i] = 0;
    __syncthreads();
    for (int i = beg + t; i < end; i += 1024)
        atomicAdd(&hist[dst[i] >> BSHIFT], 1);
    __syncthreads();
    for (int i = t; i < nb; i += 1024)
        ofs[i] = hist[i] ? atomicAdd(&cursor[i], hist[i]) : 0;
    __syncthreads();
    for (int i = beg + t; i < end; i += 1024) {
        int s = src[i], d = dst[i];
        int pos = atomicAdd(&ofs[d >> BSHIFT], 1);
        ebuf[pos] = (s << BSHIFT) | (d & (BNODES - 1));
    }
}

// ---------------- per-bucket counting sort -> per-node CSR + row_ptr + dinv ----------------

__global__ __launch_bounds__(256) void k_sort(const int* __restrict__ ebuf,
                                              const int* __restrict__ base,
                                              int* __restrict__ csr,
                                              int* __restrict__ row_ptr,
                                              float* __restrict__ dinv, int n) {
    __shared__ int cnt[BNODES];
    __shared__ int sh[BNODES];
    __shared__ int cur[BNODES];
    int b = blockIdx.x, t = threadIdx.x;
    if (t < BNODES) cnt[t] = 0;
    __syncthreads();
    int st = base[b], en = base[b + 1];
    for (int i = st + t; i < en; i += 256)
        atomicAdd(&cnt[ebuf[i] & (BNODES - 1)], 1);
    __syncthreads();
    if (t < BNODES) sh[t] = cnt[t];
    __syncthreads();
    for (int off = 1; off < BNODES; off <<= 1) {
        int x = (t >= off && t < BNODES) ? sh[t - off] : 0;
        __syncthreads();
        if (t < BNODES) sh[t] += x;
        __syncthreads();
    }
    if (t < BNODES) {
        int excl = (t > 0) ? sh[t - 1] : 0;
        int node = b * BNODES + t;
        if (node < n) {
            row_ptr[node] = st + excl;
            dinv[node] = rsqrtf((float)cnt[t] + 1.0f);
        }
        cur[t] = st + excl;
    }
    __syncthreads();
    for (int i = st + t; i < en; i += 256) {
        int ep = ebuf[i];
        int pos = atomicAdd(&cur[ep & (BNODES - 1)], 1);
        csr[pos] = ep >> BSHIFT;
    }
}

// ---------------- layer 1 GEMM: g1b = bf16( dinv * (x @ W1) ) ----------------
// 2 threads per row, feature-half per wave-uniform h -> W1 via scalar loads,
// x streamed as float4, registers only (no LDS, no syncthreads).

__global__ __launch_bounds__(256) void k_gemm1(const float* __restrict__ x,
                                               const float* __restrict__ W1,
                                               const float* __restrict__ dinv,
                                               unsigned short* __restrict__ g1b, int n) {
    int t = threadIdx.x;
    int h = __builtin_amdgcn_readfirstlane(t >> 7);  // wave-uniform feature half
    int row = blockIdx.x * 128 + (t & 127);
    if (row >= n) return;
    const float4* xr = (const float4*)(x + (size_t)row * F_IN);
    const float* Wh = W1 + h * 8;  // uniform -> s_load path
    float acc[8] = {0, 0, 0, 0, 0, 0, 0, 0};
#pragma unroll 8
    for (int kq = 0; kq < 32; ++kq) {
        float4 xv = xr[kq];
        int k0 = kq * 4;
#pragma unroll
        for (int j = 0; j < 8; ++j) {
            acc[j] = fmaf(xv.x, Wh[(k0 + 0) * F_HID + j], acc[j]);
            acc[j] = fmaf(xv.y, Wh[(k0 + 1) * F_HID + j], acc[j]);
            acc[j] = fmaf(xv.z, Wh[(k0 + 2) * F_HID + j], acc[j]);
            acc[j] = fmaf(xv.w, Wh[(k0 + 3) * F_HID + j], acc[j]);
        }
    }
    float di = dinv[row];
    unsigned pk[4];
#pragma unroll
    for (int j = 0; j < 4; ++j) {
        unsigned lo = bf16rn(acc[2 * j] * di);
        unsigned hi = bf16rn(acc[2 * j + 1] * di);
        pk[j] = lo | (hi << 16);
    }
    ((uint4*)g1b)[(size_t)row * 2 + h] = make_uint4(pk[0], pk[1], pk[2], pk[3]);
}

// ---------------- layer 1 gather + relu + gemm2, NO atomics ----------------
// 2 lanes per node: register accumulation over CSR neighbor list (bf16 rows,
// L2-resident); pair exchanges hidden halves via shfl_xor; W2 applied inline.

__global__ __launch_bounds__(256) void k_gather1(const int* __restrict__ row_ptr,
                                                 const int* __restrict__ csr,
                                                 const float* __restrict__ dinv,
                                                 const unsigned short* __restrict__ g1b,
                                                 const float* __restrict__ b1,
                                                 const float* __restrict__ W2,
                                                 float* __restrict__ g2, int n) {
    int t = threadIdx.x;
    int node = blockIdx.x * 128 + (t >> 1);
    int q = t & 1;
    if (node >= n) return;
    int st = row_ptr[node], en = row_ptr[node + 1];
    const uint4* rows = (const uint4*)g1b;  // half-row q of node i at rows[i*2+q]
    float a[8];
    uint4 v = rows[(size_t)node * 2 + q];  // self-loop
    a[0] = b2f(v.x & 0xffffu); a[1] = b2f(v.x >> 16);
    a[2] = b2f(v.y & 0xffffu); a[3] = b2f(v.y >> 16);
    a[4] = b2f(v.z & 0xffffu); a[5] = b2f(v.z >> 16);
    a[6] = b2f(v.w & 0xffffu); a[7] = b2f(v.w >> 16);
    int k = st;
    for (; k + 2 <= en; k += 2) {
        int s0 = csr[k], s1 = csr[k + 1];
        uint4 v0 = rows[(size_t)s0 * 2 + q];
        uint4 v1 = rows[(size_t)s1 * 2 + q];
        a[0] += b2f(v0.x & 0xffffu) + b2f(v1.x & 0xffffu);
        a[1] += b2f(v0.x >> 16)     + b2f(v1.x >> 16);
        a[2] += b2f(v0.y & 0xffffu) + b2f(v1.y & 0xffffu);
        a[3] += b2f(v0.y >> 16)     + b2f(v1.y >> 16);
        a[4] += b2f(v0.z & 0xffffu) + b2f(v1.z & 0xffffu);
        a[5] += b2f(v0.z >> 16)     + b2f(v1.z >> 16);
        a[6] += b2f(v0.w & 0xffffu) + b2f(v1.w & 0xffffu);
        a[7] += b2f(v0.w >> 16)     + b2f(v1.w >> 16);
    }
    if (k < en) {
        int s0 = csr[k];
        uint4 v0 = rows[(size_t)s0 * 2 + q];
        a[0] += b2f(v0.x & 0xffffu); a[1] += b2f(v0.x >> 16);
        a[2] += b2f(v0.y & 0xffffu); a[3] += b2f(v0.y >> 16);
        a[4] += b2f(v0.z & 0xffffu); a[5] += b2f(v0.z >> 16);
        a[6] += b2f(v0.w & 0xffffu); a[7] += b2f(v0.w >> 16);
    }
    float di = dinv[node];
    float h_own[8], h_oth[8];
#pragma unroll
    for (int j = 0; j < 8; ++j)
        h_own[j] = fmaxf(di * a[j] + b1[q * 8 + j], 0.0f);
#pragma unroll
    for (int j = 0; j < 8; ++j) h_oth[j] = __shfl_xor(h_own[j], 1);
    float flo[8], fhi[8];
#pragma unroll
    for (int j = 0; j < 8; ++j) {
        flo[j] = (q == 0) ? h_own[j] : h_oth[j];  // features 0..7
        fhi[j] = (q == 0) ? h_oth[j] : h_own[j];  // features 8..15
    }
    int jj0 = q * 4;
    float o0 = 0, o1 = 0, o2 = 0, o3 = 0;
#pragma unroll
    for (int kk = 0; kk < 16; ++kk) {
        float hk = (kk < 8) ? flo[kk] : fhi[kk - 8];
        const float* wr = &W2[kk * F_OUT + jj0];
        o0 = fmaf(hk, wr[0], o0);
        o1 = fmaf(hk, wr[1], o1);
        o2 = fmaf(hk, wr[2], o2);
        o3 = fmaf(hk, wr[3], o3);
    }
    *(float4*)&g2[(size_t)node * F_OUT + jj0] =
        make_float4(o0 * di, o1 * di, o2 * di, o3 * di);
}

// ---------------- layer 2 gather + bias + log_softmax, NO atomics ----------------

__global__ __launch_bounds__(256) void k_gather2(const int* __restrict__ row_ptr,
                                                 const int* __restrict__ csr,
                                                 const float* __restrict__ dinv,
                                                 const float* __restrict__ g2,
                                                 const float* __restrict__ b2,
                                                 float* __restrict__ out, int n) {
    int t = threadIdx.x;
    int node = blockIdx.x * 128 + (t >> 1);
    int q = t & 1;
    if (node >= n) return;
    int st = row_ptr[node], en = row_ptr[node + 1];
    const float4* rows = (const float4*)g2;  // half-row q of node i at rows[i*2+q]
    float4 s4 = rows[(size_t)node * 2 + q];  // self-loop
    float a0 = s4.x, a1 = s4.y, a2 = s4.z, a3 = s4.w;
    int k = st;
    for (; k + 2 <= en; k += 2) {
        int s0 = csr[k], s1 = csr[k + 1];
        float4 v0 = rows[(size_t)s0 * 2 + q];
        float4 v1 = rows[(size_t)s1 * 2 + q];
        a0 += v0.x + v1.x; a1 += v0.y + v1.y;
        a2 += v0.z + v1.z; a3 += v0.w + v1.w;
    }
    if (k < en) {
        float4 v0 = rows[(size_t)csr[k] * 2 + q];
        a0 += v0.x; a1 += v0.y; a2 += v0.z; a3 += v0.w;
    }
    float di = dinv[node];
    float v0 = di * a0 + b2[q * 4 + 0];
    float v1 = di * a1 + b2[q * 4 + 1];
    float v2 = di * a2 + b2[q * 4 + 2];
    float v3 = di * a3 + b2[q * 4 + 3];
    float m = fmaxf(fmaxf(v0, v1), fmaxf(v2, v3));
    m = fmaxf(m, __shfl_xor(m, 1));
    float ss = expf(v0 - m) + expf(v1 - m) + expf(v2 - m) + expf(v3 - m);
    ss += __shfl_xor(ss, 1);
    float ls = m + logf(ss);
    *(float4*)&out[(size_t)node * F_OUT + q * 4] =
        make_float4(v0 - ls, v1 - ls, v2 - ls, v3 - ls);
}

// ---------------- launch ----------------

extern "C" void kernel_launch(void* const* d_in, const int* in_sizes, int n_in,
                              void* d_out, int out_size, void* d_ws, size_t ws_size,
                              hipStream_t stream) {
    const float* x  = (const float*)d_in[0];
    const int*   ei = (const int*)d_in[1];
    const float* W1 = (const float*)d_in[2];
    const float* b1 = (const float*)d_in[3];
    const float* W2 = (const float*)d_in[4];
    const float* b2 = (const float*)d_in[5];
    float* out = (float*)d_out;

    const int n = in_sizes[0] / F_IN;   // 100000
    const int e = in_sizes[1] / 2;      // 3200000
    const int* src = ei;
    const int* dst = ei + e;
    const int nb = (n + BNODES - 1) / BNODES;  // 782

    char* w = (char*)d_ws;
    float* dinv         = (float*)w; w += (size_t)n * 4;
    int* ebuf           = (int*)w;   w += (size_t)e * 4;
    int* csr            = (int*)w;   w += (size_t)e * 4;
    int* row_ptr        = (int*)w;   w += (size_t)(n + 4) * 4;
    int* bucket_cnt     = (int*)w;   w += (size_t)(nb + 4) * 4;
    int* base           = (int*)w;   w += (size_t)(nb + 4) * 4;
    int* cursor         = (int*)w;   w += (size_t)(nb + 4) * 4;
    w = (char*)(((size_t)w + 15) & ~(size_t)15);
    unsigned short* g1b = (unsigned short*)w; w += (size_t)n * F_HID * 2;
    w = (char*)(((size_t)w + 15) & ~(size_t)15);
    float* g2           = (float*)w; w += (size_t)n * F_OUT * 4;

    k_zero<<<(nb + 255) / 256, 256, 0, stream>>>(bucket_cnt, nb);
    k_hist<<<256, 256, 0, stream>>>(dst, bucket_cnt, e, nb);
    k_scan<<<1, 256, 0, stream>>>(bucket_cnt, base, cursor, row_ptr, nb, e, n);
    k_bucket<<<(e + CHUNK - 1) / CHUNK, 1024, 0, stream>>>(src, dst, cursor, ebuf, e, nb);
    k_sort<<<nb, 256, 0, stream>>>(ebuf, base, csr, row_ptr, dinv, n);
    k_gemm1<<<(n + 127) / 128, 256, 0, stream>>>(x, W1, dinv, g1b, n);
    k_gather1<<<(n + 127) / 128, 256, 0, stream>>>(row_ptr, csr, dinv, g1b, b1, W2, g2, n);
    k_gather2<<<(n + 127) / 128, 256, 0, stream>>>(row_ptr, csr, dinv, g2, b2, out, n);
}

// Round 13
// 251.957 us; speedup vs baseline: 3.1115x; 1.1068x over previous
//
#include <hip/hip_runtime.h>
#include <math.h>

#define F_IN 128
#define F_HID 16
#define F_OUT 8
#define BSHIFT 7
#define BNODES 128   // nodes per bucket = 1<<BSHIFT
#define MAXNB 1024   // LDS arrays sized for nb <= 1024 (nb = 782)
#define CHUNK 8192   // edges per block in k_bucket
#define SORTBUF 8192 // LDS staging capacity in k_sort (mean bucket = 4092 edges)

// bf16 helpers: round-to-nearest-even pack, cheap unpack
__device__ inline unsigned bf16rn(float x) {
    unsigned u = __float_as_uint(x);
    u += 0x7fffu + ((u >> 16) & 1u);
    return u >> 16;
}
__device__ inline float b2f(unsigned h) { return __uint_as_float(h << 16); }

// ---------------- zero bucket counters ----------------

__global__ void k_zero(int* __restrict__ p, int m) {
    int i = blockIdx.x * blockDim.x + threadIdx.x;
    if (i < m) p[i] = 0;
}

// ---------------- bucket histogram (LDS-aggregated) ----------------

__global__ __launch_bounds__(256) void k_hist(const int* __restrict__ dst,
                                              int* __restrict__ bucket_cnt,
                                              int e, int nb) {
    __shared__ int sh[MAXNB];
    int t = threadIdx.x;
    for (int i = t; i < nb; i += 256) sh[i] = 0;
    __syncthreads();
    int stride = gridDim.x * 256;
    for (int i = blockIdx.x * 256 + t; i < e; i += stride)
        atomicAdd(&sh[dst[i] >> BSHIFT], 1);
    __syncthreads();
    for (int i = t; i < nb; i += 256)
        if (sh[i]) atomicAdd(&bucket_cnt[i], sh[i]);
}

// ---------------- exclusive scan of bucket counts (nb <= 1024, 1 block) ----------------

__global__ __launch_bounds__(256) void k_scan(const int* __restrict__ bucket_cnt,
                                              int* __restrict__ base,
                                              int* __restrict__ cursor,
                                              int* __restrict__ row_ptr, int nb, int e, int n) {
    __shared__ int sh[256];
    int t = threadIdx.x;
    int v[4], s = 0;
#pragma unroll
    for (int q = 0; q < 4; ++q) {
        int i = t * 4 + q;
        v[q] = (i < nb) ? bucket_cnt[i] : 0;
        s += v[q];
    }
    sh[t] = s;
    __syncthreads();
    for (int off = 1; off < 256; off <<= 1) {
        int x = (t >= off) ? sh[t - off] : 0;
        __syncthreads();
        sh[t] += x;
        __syncthreads();
    }
    int run = (t > 0) ? sh[t - 1] : 0;
#pragma unroll
    for (int q = 0; q < 4; ++q) {
        int i = t * 4 + q;
        if (i < nb) { base[i] = run; cursor[i] = run; }
        run += v[q];
    }
    if (t == 0) { base[nb] = e; row_ptr[n] = e; }  // sentinels
}

// ---------------- bucket scatter: LDS-sort chunk, then stride-1 global dump ----------------
// Per 8192-edge chunk: LDS hist (rank-returning) -> LDS scan -> one global
// atomicAdd per (block,bucket) -> scatter into bucket-ordered LDS buffer ->
// coalesced write-out (consecutive j hit consecutive addresses within runs).

__global__ __launch_bounds__(1024) void k_bucket(const int* __restrict__ src,
                                                 const int* __restrict__ dst,
                                                 int* __restrict__ cursor,
                                                 int* __restrict__ ebuf, int e, int nb) {
    __shared__ int hist[MAXNB];
    __shared__ int lofs[MAXNB];
    __shared__ int delta[MAXNB];
    __shared__ int sorted[CHUNK];
    __shared__ unsigned short bkt[CHUNK];
    int t = threadIdx.x;
    int beg = blockIdx.x * CHUNK;
    int end = min(beg + CHUNK, e);
    int cn = end - beg;
    for (int i = t; i < nb; i += 1024) hist[i] = 0;
    __syncthreads();
    // load + rank (static-indexed unroll: 8 edges/thread max)
    int myw[8], mybr[8];
#pragma unroll
    for (int u = 0; u < 8; ++u) {
        int i = beg + t + u * 1024;
        if (i < end) {
            int s = src[i], d = dst[i];
            int b = d >> BSHIFT;
            myw[u] = (s << BSHIFT) | (d & (BNODES - 1));
            int r = atomicAdd(&hist[b], 1);
            mybr[u] = (b << 16) | r;  // b<1024, r<8192
        }
    }
    __syncthreads();
    // exclusive scan of hist over 1024 entries (Hillis-Steele)
    int v = (t < nb) ? hist[t] : 0;
    lofs[t] = v;
    __syncthreads();
    for (int off = 1; off < 1024; off <<= 1) {
        int x = (t >= off) ? lofs[t - off] : 0;
        __syncthreads();
        lofs[t] += x;
        __syncthreads();
    }
    int excl = lofs[t] - v;
    lofs[t] = excl;  // own-index rewrite, no race
    if (t < nb) {
        int g = v ? atomicAdd(&cursor[t], v) : 0;
        delta[t] = g - excl;
    }
    __syncthreads();
    // scatter into LDS bucket order
#pragma unroll
    for (int u = 0; u < 8; ++u) {
        int i = beg + t + u * 1024;
        if (i < end) {
            int b = mybr[u] >> 16, r = mybr[u] & 0xffff;
            int p = lofs[b] + r;
            sorted[p] = myw[u];
            bkt[p] = (unsigned short)b;
        }
    }
    __syncthreads();
    // coalesced dump: global pos = delta[b] + j, stride-1 within runs
    for (int j = t; j < cn; j += 1024)
        ebuf[delta[bkt[j]] + j] = sorted[j];
}

// ---------------- per-bucket counting sort -> CSR via LDS staging ----------------
// Sorted result staged in LDS, dumped stride-1 (csr range per block is contiguous).

__global__ __launch_bounds__(256) void k_sort(const int* __restrict__ ebuf,
                                              const int* __restrict__ base,
                                              int* __restrict__ csr,
                                              int* __restrict__ row_ptr,
                                              float* __restrict__ dinv, int n) {
    __shared__ int cnt[BNODES];
    __shared__ int sh[BNODES];
    __shared__ int cur[BNODES];
    __shared__ int buf[SORTBUF];
    int b = blockIdx.x, t = threadIdx.x;
    if (t < BNODES) cnt[t] = 0;
    __syncthreads();
    int st = base[b], en = base[b + 1];
    int cn = en - st;
    for (int i = st + t; i < en; i += 256)
        atomicAdd(&cnt[ebuf[i] & (BNODES - 1)], 1);
    __syncthreads();
    if (t < BNODES) sh[t] = cnt[t];
    __syncthreads();
    for (int off = 1; off < BNODES; off <<= 1) {
        int x = (t >= off && t < BNODES) ? sh[t - off] : 0;
        __syncthreads();
        if (t < BNODES) sh[t] += x;
        __syncthreads();
    }
    if (t < BNODES) {
        int excl = (t > 0) ? sh[t - 1] : 0;
        int node = b * BNODES + t;
        if (node < n) {
            row_ptr[node] = st + excl;
            dinv[node] = rsqrtf((float)cnt[t] + 1.0f);
        }
        cur[t] = excl;  // LOCAL offset
    }
    __syncthreads();
    if (cn <= SORTBUF) {
        for (int i = st + t; i < en; i += 256) {
            int ep = ebuf[i];
            int p = atomicAdd(&cur[ep & (BNODES - 1)], 1);
            buf[p] = ep >> BSHIFT;
        }
        __syncthreads();
        for (int j = t; j < cn; j += 256) csr[st + j] = buf[j];
    } else {  // safety fallback (never expected for this graph)
        if (t < BNODES) cur[t] += st;
        __syncthreads();
        for (int i = st + t; i < en; i += 256) {
            int ep = ebuf[i];
            int pos = atomicAdd(&cur[ep & (BNODES - 1)], 1);
            csr[pos] = ep >> BSHIFT;
        }
    }
}

// ---------------- layer 1 GEMM: g1b = bf16( dinv * (x @ W1) ) ----------------
// 2 threads per row, feature-half per wave-uniform h -> W1 via scalar loads,
// x streamed as float4, registers only (no LDS, no syncthreads).

__global__ __launch_bounds__(256) void k_gemm1(const float* __restrict__ x,
                                               const float* __restrict__ W1,
                                               const float* __restrict__ dinv,
                                               unsigned short* __restrict__ g1b, int n) {
    int t = threadIdx.x;
    int h = __builtin_amdgcn_readfirstlane(t >> 7);  // wave-uniform feature half
    int row = blockIdx.x * 128 + (t & 127);
    if (row >= n) return;
    const float4* xr = (const float4*)(x + (size_t)row * F_IN);
    const float* Wh = W1 + h * 8;  // uniform -> s_load path
    float acc[8] = {0, 0, 0, 0, 0, 0, 0, 0};
#pragma unroll 8
    for (int kq = 0; kq < 32; ++kq) {
        float4 xv = xr[kq];
        int k0 = kq * 4;
#pragma unroll
        for (int j = 0; j < 8; ++j) {
            acc[j] = fmaf(xv.x, Wh[(k0 + 0) * F_HID + j], acc[j]);
            acc[j] = fmaf(xv.y, Wh[(k0 + 1) * F_HID + j], acc[j]);
            acc[j] = fmaf(xv.z, Wh[(k0 + 2) * F_HID + j], acc[j]);
            acc[j] = fmaf(xv.w, Wh[(k0 + 3) * F_HID + j], acc[j]);
        }
    }
    float di = dinv[row];
    unsigned pk[4];
#pragma unroll
    for (int j = 0; j < 4; ++j) {
        unsigned lo = bf16rn(acc[2 * j] * di);
        unsigned hi = bf16rn(acc[2 * j + 1] * di);
        pk[j] = lo | (hi << 16);
    }
    ((uint4*)g1b)[(size_t)row * 2 + h] = make_uint4(pk[0], pk[1], pk[2], pk[3]);
}

// ---------------- layer 1 gather + relu + gemm2, NO atomics ----------------
// 2 lanes per node: register accumulation over CSR neighbor list (bf16 rows,
// L2-resident); pair exchanges hidden halves via shfl_xor; W2 applied inline.

__global__ __launch_bounds__(256) void k_gather1(const int* __restrict__ row_ptr,
                                                 const int* __restrict__ csr,
                                                 const float* __restrict__ dinv,
                                                 const unsigned short* __restrict__ g1b,
                                                 const float* __restrict__ b1,
                                                 const float* __restrict__ W2,
                                                 float* __restrict__ g2, int n) {
    int t = threadIdx.x;
    int node = blockIdx.x * 128 + (t >> 1);
    int q = t & 1;
    if (node >= n) return;
    int st = row_ptr[node], en = row_ptr[node + 1];
    const uint4* rows = (const uint4*)g1b;  // half-row q of node i at rows[i*2+q]
    float a[8];
    uint4 v = rows[(size_t)node * 2 + q];  // self-loop
    a[0] = b2f(v.x & 0xffffu); a[1] = b2f(v.x >> 16);
    a[2] = b2f(v.y & 0xffffu); a[3] = b2f(v.y >> 16);
    a[4] = b2f(v.z & 0xffffu); a[5] = b2f(v.z >> 16);
    a[6] = b2f(v.w & 0xffffu); a[7] = b2f(v.w >> 16);
    int k = st;
    for (; k + 2 <= en; k += 2) {
        int s0 = csr[k], s1 = csr[k + 1];
        uint4 v0 = rows[(size_t)s0 * 2 + q];
        uint4 v1 = rows[(size_t)s1 * 2 + q];
        a[0] += b2f(v0.x & 0xffffu) + b2f(v1.x & 0xffffu);
        a[1] += b2f(v0.x >> 16)     + b2f(v1.x >> 16);
        a[2] += b2f(v0.y & 0xffffu) + b2f(v1.y & 0xffffu);
        a[3] += b2f(v0.y >> 16)     + b2f(v1.y >> 16);
        a[4] += b2f(v0.z & 0xffffu) + b2f(v1.z & 0xffffu);
        a[5] += b2f(v0.z >> 16)     + b2f(v1.z >> 16);
        a[6] += b2f(v0.w & 0xffffu) + b2f(v1.w & 0xffffu);
        a[7] += b2f(v0.w >> 16)     + b2f(v1.w >> 16);
    }
    if (k < en) {
        int s0 = csr[k];
        uint4 v0 = rows[(size_t)s0 * 2 + q];
        a[0] += b2f(v0.x & 0xffffu); a[1] += b2f(v0.x >> 16);
        a[2] += b2f(v0.y & 0xffffu); a[3] += b2f(v0.y >> 16);
        a[4] += b2f(v0.z & 0xffffu); a[5] += b2f(v0.z >> 16);
        a[6] += b2f(v0.w & 0xffffu); a[7] += b2f(v0.w >> 16);
    }
    float di = dinv[node];
    float h_own[8], h_oth[8];
#pragma unroll
    for (int j = 0; j < 8; ++j)
        h_own[j] = fmaxf(di * a[j] + b1[q * 8 + j], 0.0f);
#pragma unroll
    for (int j = 0; j < 8; ++j) h_oth[j] = __shfl_xor(h_own[j], 1);
    float flo[8], fhi[8];
#pragma unroll
    for (int j = 0; j < 8; ++j) {
        flo[j] = (q == 0) ? h_own[j] : h_oth[j];  // features 0..7
        fhi[j] = (q == 0) ? h_oth[j] : h_own[j];  // features 8..15
    }
    int jj0 = q * 4;
    float o0 = 0, o1 = 0, o2 = 0, o3 = 0;
#pragma unroll
    for (int kk = 0; kk < 16; ++kk) {
        float hk = (kk < 8) ? flo[kk] : fhi[kk - 8];
        const float* wr = &W2[kk * F_OUT + jj0];
        o0 = fmaf(hk, wr[0], o0);
        o1 = fmaf(hk, wr[1], o1);
        o2 = fmaf(hk, wr[2], o2);
        o3 = fmaf(hk, wr[3], o3);
    }
    *(float4*)&g2[(size_t)node * F_OUT + jj0] =
        make_float4(o0 * di, o1 * di, o2 * di, o3 * di);
}

// ---------------- layer 2 gather + bias + log_softmax, NO atomics ----------------

__global__ __launch_bounds__(256) void k_gather2(const int* __restrict__ row_ptr,
                                                 const int* __restrict__ csr,
                                                 const float* __restrict__ dinv,
                                                 const float* __restrict__ g2,
                                                 const float* __restrict__ b2,
                                                 float* __restrict__ out, int n) {
    int t = threadIdx.x;
    int node = blockIdx.x * 128 + (t >> 1);
    int q = t & 1;
    if (node >= n) return;
    int st = row_ptr[node], en = row_ptr[node + 1];
    const float4* rows = (const float4*)g2;  // half-row q of node i at rows[i*2+q]
    float4 s4 = rows[(size_t)node * 2 + q];  // self-loop
    float a0 = s4.x, a1 = s4.y, a2 = s4.z, a3 = s4.w;
    int k = st;
    for (; k + 2 <= en; k += 2) {
        int s0 = csr[k], s1 = csr[k + 1];
        float4 v0 = rows[(size_t)s0 * 2 + q];
        float4 v1 = rows[(size_t)s1 * 2 + q];
        a0 += v0.x + v1.x; a1 += v0.y + v1.y;
        a2 += v0.z + v1.z; a3 += v0.w + v1.w;
    }
    if (k < en) {
        float4 v0 = rows[(size_t)csr[k] * 2 + q];
        a0 += v0.x; a1 += v0.y; a2 += v0.z; a3 += v0.w;
    }
    float di = dinv[node];
    float v0 = di * a0 + b2[q * 4 + 0];
    float v1 = di * a1 + b2[q * 4 + 1];
    float v2 = di * a2 + b2[q * 4 + 2];
    float v3 = di * a3 + b2[q * 4 + 3];
    float m = fmaxf(fmaxf(v0, v1), fmaxf(v2, v3));
    m = fmaxf(m, __shfl_xor(m, 1));
    float ss = expf(v0 - m) + expf(v1 - m) + expf(v2 - m) + expf(v3 - m);
    ss += __shfl_xor(ss, 1);
    float ls = m + logf(ss);
    *(float4*)&out[(size_t)node * F_OUT + q * 4] =
        make_float4(v0 - ls, v1 - ls, v2 - ls, v3 - ls);
}

// ---------------- launch ----------------

extern "C" void kernel_launch(void* const* d_in, const int* in_sizes, int n_in,
                              void* d_out, int out_size, void* d_ws, size_t ws_size,
                              hipStream_t stream) {
    const float* x  = (const float*)d_in[0];
    const int*   ei = (const int*)d_in[1];
    const float* W1 = (const float*)d_in[2];
    const float* b1 = (const float*)d_in[3];
    const float* W2 = (const float*)d_in[4];
    const float* b2 = (const float*)d_in[5];
    float* out = (float*)d_out;

    const int n = in_sizes[0] / F_IN;   // 100000
    const int e = in_sizes[1] / 2;      // 3200000
    const int* src = ei;
    const int* dst = ei + e;
    const int nb = (n + BNODES - 1) / BNODES;  // 782

    char* w = (char*)d_ws;
    float* dinv         = (float*)w; w += (size_t)n * 4;
    int* ebuf           = (int*)w;   w += (size_t)e * 4;
    int* csr            = (int*)w;   w += (size_t)e * 4;
    int* row_ptr        = (int*)w;   w += (size_t)(n + 4) * 4;
    int* bucket_cnt     = (int*)w;   w += (size_t)(nb + 4) * 4;
    int* base           = (int*)w;   w += (size_t)(nb + 4) * 4;
    int* cursor         = (int*)w;   w += (size_t)(nb + 4) * 4;
    w = (char*)(((size_t)w + 15) & ~(size_t)15);
    unsigned short* g1b = (unsigned short*)w; w += (size_t)n * F_HID * 2;
    w = (char*)(((size_t)w + 15) & ~(size_t)15);
    float* g2           = (float*)w; w += (size_t)n * F_OUT * 4;

    k_zero<<<(nb + 255) / 256, 256, 0, stream>>>(bucket_cnt, nb);
    k_hist<<<256, 256, 0, stream>>>(dst, bucket_cnt, e, nb);
    k_scan<<<1, 256, 0, stream>>>(bucket_cnt, base, cursor, row_ptr, nb, e, n);
    k_bucket<<<(e + CHUNK - 1) / CHUNK, 1024, 0, stream>>>(src, dst, cursor, ebuf, e, nb);
    k_sort<<<nb, 256, 0, stream>>>(ebuf, base, csr, row_ptr, dinv, n);
    k_gemm1<<<(n + 127) / 128, 256, 0, stream>>>(x, W1, dinv, g1b, n);
    k_gather1<<<(n + 127) / 128, 256, 0, stream>>>(row_ptr, csr, dinv, g1b, b1, W2, g2, n);
    k_gather2<<<(n + 127) / 128, 256, 0, stream>>>(row_ptr, csr, dinv, g2, b2, out, n);
}

// Round 14
// 238.605 us; speedup vs baseline: 3.2857x; 1.0560x over previous
//
#include <hip/hip_runtime.h>
#include <math.h>

#define F_IN 128
#define F_HID 16
#define F_OUT 8
#define BSHIFT 7
#define BNODES 128   // nodes per bucket = 1<<BSHIFT
#define MAXNB 1024   // LDS arrays sized for nb <= 1024 (nb = 782)
#define CHUNK 8192   // edges per block in k_bucket
#define SORTBUF 8192 // LDS staging capacity in k_sort (mean bucket = 4092 edges)

// bf16 helpers: round-to-nearest-even pack, cheap unpack
__device__ inline unsigned bf16rn(float x) {
    unsigned u = __float_as_uint(x);
    u += 0x7fffu + ((u >> 16) & 1u);
    return u >> 16;
}
__device__ inline float b2f(unsigned h) { return __uint_as_float(h << 16); }

// ---------------- zero bucket counters ----------------

__global__ void k_zero(int* __restrict__ p, int m) {
    int i = blockIdx.x * blockDim.x + threadIdx.x;
    if (i < m) p[i] = 0;
}

// ---------------- bucket histogram (LDS-aggregated) ----------------

__global__ __launch_bounds__(256) void k_hist(const int* __restrict__ dst,
                                              int* __restrict__ bucket_cnt,
                                              int e, int nb) {
    __shared__ int sh[MAXNB];
    int t = threadIdx.x;
    for (int i = t; i < nb; i += 256) sh[i] = 0;
    __syncthreads();
    int stride = gridDim.x * 256;
    for (int i = blockIdx.x * 256 + t; i < e; i += stride)
        atomicAdd(&sh[dst[i] >> BSHIFT], 1);
    __syncthreads();
    for (int i = t; i < nb; i += 256)
        if (sh[i]) atomicAdd(&bucket_cnt[i], sh[i]);
}

// ---------------- exclusive scan of bucket counts (nb <= 1024, 1 block) ----------------

__global__ __launch_bounds__(256) void k_scan(const int* __restrict__ bucket_cnt,
                                              int* __restrict__ base,
                                              int* __restrict__ cursor,
                                              int* __restrict__ row_ptr, int nb, int e, int n) {
    __shared__ int sh[256];
    int t = threadIdx.x;
    int v[4], s = 0;
#pragma unroll
    for (int q = 0; q < 4; ++q) {
        int i = t * 4 + q;
        v[q] = (i < nb) ? bucket_cnt[i] : 0;
        s += v[q];
    }
    sh[t] = s;
    __syncthreads();
    for (int off = 1; off < 256; off <<= 1) {
        int x = (t >= off) ? sh[t - off] : 0;
        __syncthreads();
        sh[t] += x;
        __syncthreads();
    }
    int run = (t > 0) ? sh[t - 1] : 0;
#pragma unroll
    for (int q = 0; q < 4; ++q) {
        int i = t * 4 + q;
        if (i < nb) { base[i] = run; cursor[i] = run; }
        run += v[q];
    }
    if (t == 0) { base[nb] = e; row_ptr[n] = e; }  // sentinels
}

// ---------------- bucket scatter: LDS-sort chunk, then stride-1 global dump ----------------

__global__ __launch_bounds__(1024) void k_bucket(const int* __restrict__ src,
                                                 const int* __restrict__ dst,
                                                 int* __restrict__ cursor,
                                                 int* __restrict__ ebuf, int e, int nb) {
    __shared__ int hist[MAXNB];
    __shared__ int lofs[MAXNB];
    __shared__ int delta[MAXNB];
    __shared__ int sorted[CHUNK];
    __shared__ unsigned short bkt[CHUNK];
    int t = threadIdx.x;
    int beg = blockIdx.x * CHUNK;
    int end = min(beg + CHUNK, e);
    int cn = end - beg;
    for (int i = t; i < nb; i += 1024) hist[i] = 0;
    __syncthreads();
    // load + rank (static-indexed unroll: 8 edges/thread max)
    int myw[8], mybr[8];
#pragma unroll
    for (int u = 0; u < 8; ++u) {
        int i = beg + t + u * 1024;
        if (i < end) {
            int s = src[i], d = dst[i];
            int b = d >> BSHIFT;
            myw[u] = (s << BSHIFT) | (d & (BNODES - 1));
            int r = atomicAdd(&hist[b], 1);
            mybr[u] = (b << 16) | r;  // b<1024, r<8192
        }
    }
    __syncthreads();
    // exclusive scan of hist over 1024 entries (Hillis-Steele)
    int v = (t < nb) ? hist[t] : 0;
    lofs[t] = v;
    __syncthreads();
    for (int off = 1; off < 1024; off <<= 1) {
        int x = (t >= off) ? lofs[t - off] : 0;
        __syncthreads();
        lofs[t] += x;
        __syncthreads();
    }
    int excl = lofs[t] - v;
    lofs[t] = excl;  // own-index rewrite, no race
    if (t < nb) {
        int g = v ? atomicAdd(&cursor[t], v) : 0;
        delta[t] = g - excl;
    }
    __syncthreads();
    // scatter into LDS bucket order
#pragma unroll
    for (int u = 0; u < 8; ++u) {
        int i = beg + t + u * 1024;
        if (i < end) {
            int b = mybr[u] >> 16, r = mybr[u] & 0xffff;
            int p = lofs[b] + r;
            sorted[p] = myw[u];
            bkt[p] = (unsigned short)b;
        }
    }
    __syncthreads();
    // coalesced dump: global pos = delta[b] + j, stride-1 within runs
    for (int j = t; j < cn; j += 1024)
        ebuf[delta[bkt[j]] + j] = sorted[j];
}

// ---------------- per-bucket counting sort -> CSR via LDS staging ----------------

__global__ __launch_bounds__(256) void k_sort(const int* __restrict__ ebuf,
                                              const int* __restrict__ base,
                                              int* __restrict__ csr,
                                              int* __restrict__ row_ptr,
                                              float* __restrict__ dinv, int n) {
    __shared__ int cnt[BNODES];
    __shared__ int sh[BNODES];
    __shared__ int cur[BNODES];
    __shared__ int buf[SORTBUF];
    int b = blockIdx.x, t = threadIdx.x;
    if (t < BNODES) cnt[t] = 0;
    __syncthreads();
    int st = base[b], en = base[b + 1];
    int cn = en - st;
    for (int i = st + t; i < en; i += 256)
        atomicAdd(&cnt[ebuf[i] & (BNODES - 1)], 1);
    __syncthreads();
    if (t < BNODES) sh[t] = cnt[t];
    __syncthreads();
    for (int off = 1; off < BNODES; off <<= 1) {
        int x = (t >= off && t < BNODES) ? sh[t - off] : 0;
        __syncthreads();
        if (t < BNODES) sh[t] += x;
        __syncthreads();
    }
    if (t < BNODES) {
        int excl = (t > 0) ? sh[t - 1] : 0;
        int node = b * BNODES + t;
        if (node < n) {
            row_ptr[node] = st + excl;
            dinv[node] = rsqrtf((float)cnt[t] + 1.0f);
        }
        cur[t] = excl;  // LOCAL offset
    }
    __syncthreads();
    if (cn <= SORTBUF) {
        for (int i = st + t; i < en; i += 256) {
            int ep = ebuf[i];
            int p = atomicAdd(&cur[ep & (BNODES - 1)], 1);
            buf[p] = ep >> BSHIFT;
        }
        __syncthreads();
        for (int j = t; j < cn; j += 256) csr[st + j] = buf[j];
    } else {  // safety fallback (never expected for this graph)
        if (t < BNODES) cur[t] += st;
        __syncthreads();
        for (int i = st + t; i < en; i += 256) {
            int ep = ebuf[i];
            int pos = atomicAdd(&cur[ep & (BNODES - 1)], 1);
            csr[pos] = ep >> BSHIFT;
        }
    }
}

// ---------------- layer 1 GEMM: g1b = bf16( dinv * (x @ W1) ) ----------------

__global__ __launch_bounds__(256) void k_gemm1(const float* __restrict__ x,
                                               const float* __restrict__ W1,
                                               const float* __restrict__ dinv,
                                               unsigned short* __restrict__ g1b, int n) {
    int t = threadIdx.x;
    int h = __builtin_amdgcn_readfirstlane(t >> 7);  // wave-uniform feature half
    int row = blockIdx.x * 128 + (t & 127);
    if (row >= n) return;
    const float4* xr = (const float4*)(x + (size_t)row * F_IN);
    const float* Wh = W1 + h * 8;  // uniform -> s_load path
    float acc[8] = {0, 0, 0, 0, 0, 0, 0, 0};
#pragma unroll 8
    for (int kq = 0; kq < 32; ++kq) {
        float4 xv = xr[kq];
        int k0 = kq * 4;
#pragma unroll
        for (int j = 0; j < 8; ++j) {
            acc[j] = fmaf(xv.x, Wh[(k0 + 0) * F_HID + j], acc[j]);
            acc[j] = fmaf(xv.y, Wh[(k0 + 1) * F_HID + j], acc[j]);
            acc[j] = fmaf(xv.z, Wh[(k0 + 2) * F_HID + j], acc[j]);
            acc[j] = fmaf(xv.w, Wh[(k0 + 3) * F_HID + j], acc[j]);
        }
    }
    float di = dinv[row];
    unsigned pk[4];
#pragma unroll
    for (int j = 0; j < 4; ++j) {
        unsigned lo = bf16rn(acc[2 * j] * di);
        unsigned hi = bf16rn(acc[2 * j + 1] * di);
        pk[j] = lo | (hi << 16);
    }
    ((uint4*)g1b)[(size_t)row * 2 + h] = make_uint4(pk[0], pk[1], pk[2], pk[3]);
}

// ---------------- layer 1 gather + relu + gemm2, NO atomics, 8-deep MLP ----------------
// 2 lanes per node; 8 csr loads then 8 independent 16B row loads in flight.

__global__ __launch_bounds__(256) void k_gather1(const int* __restrict__ row_ptr,
                                                 const int* __restrict__ csr,
                                                 const float* __restrict__ dinv,
                                                 const unsigned short* __restrict__ g1b,
                                                 const float* __restrict__ b1,
                                                 const float* __restrict__ W2,
                                                 float* __restrict__ g2, int n) {
    int t = threadIdx.x;
    int node = blockIdx.x * 128 + (t >> 1);
    int q = t & 1;
    if (node >= n) return;
    int st = row_ptr[node], en = row_ptr[node + 1];
    const uint4* rows = (const uint4*)g1b;  // half-row q of node i at rows[i*2+q]
    float a[8];
    uint4 v = rows[(size_t)node * 2 + q];  // self-loop
    a[0] = b2f(v.x & 0xffffu); a[1] = b2f(v.x >> 16);
    a[2] = b2f(v.y & 0xffffu); a[3] = b2f(v.y >> 16);
    a[4] = b2f(v.z & 0xffffu); a[5] = b2f(v.z >> 16);
    a[6] = b2f(v.w & 0xffffu); a[7] = b2f(v.w >> 16);
    int k = st;
    for (; k + 8 <= en; k += 8) {
        int s[8];
#pragma unroll
        for (int u = 0; u < 8; ++u) s[u] = csr[k + u];
        uint4 vv[8];
#pragma unroll
        for (int u = 0; u < 8; ++u) vv[u] = rows[(size_t)s[u] * 2 + q];
#pragma unroll
        for (int u = 0; u < 8; ++u) {
            a[0] += b2f(vv[u].x & 0xffffu); a[1] += b2f(vv[u].x >> 16);
            a[2] += b2f(vv[u].y & 0xffffu); a[3] += b2f(vv[u].y >> 16);
            a[4] += b2f(vv[u].z & 0xffffu); a[5] += b2f(vv[u].z >> 16);
            a[6] += b2f(vv[u].w & 0xffffu); a[7] += b2f(vv[u].w >> 16);
        }
    }
    for (; k + 2 <= en; k += 2) {
        int s0 = csr[k], s1 = csr[k + 1];
        uint4 v0 = rows[(size_t)s0 * 2 + q];
        uint4 v1 = rows[(size_t)s1 * 2 + q];
        a[0] += b2f(v0.x & 0xffffu) + b2f(v1.x & 0xffffu);
        a[1] += b2f(v0.x >> 16)     + b2f(v1.x >> 16);
        a[2] += b2f(v0.y & 0xffffu) + b2f(v1.y & 0xffffu);
        a[3] += b2f(v0.y >> 16)     + b2f(v1.y >> 16);
        a[4] += b2f(v0.z & 0xffffu) + b2f(v1.z & 0xffffu);
        a[5] += b2f(v0.z >> 16)     + b2f(v1.z >> 16);
        a[6] += b2f(v0.w & 0xffffu) + b2f(v1.w & 0xffffu);
        a[7] += b2f(v0.w >> 16)     + b2f(v1.w >> 16);
    }
    if (k < en) {
        uint4 v0 = rows[(size_t)csr[k] * 2 + q];
        a[0] += b2f(v0.x & 0xffffu); a[1] += b2f(v0.x >> 16);
        a[2] += b2f(v0.y & 0xffffu); a[3] += b2f(v0.y >> 16);
        a[4] += b2f(v0.z & 0xffffu); a[5] += b2f(v0.z >> 16);
        a[6] += b2f(v0.w & 0xffffu); a[7] += b2f(v0.w >> 16);
    }
    float di = dinv[node];
    float h_own[8], h_oth[8];
#pragma unroll
    for (int j = 0; j < 8; ++j)
        h_own[j] = fmaxf(di * a[j] + b1[q * 8 + j], 0.0f);
#pragma unroll
    for (int j = 0; j < 8; ++j) h_oth[j] = __shfl_xor(h_own[j], 1);
    float flo[8], fhi[8];
#pragma unroll
    for (int j = 0; j < 8; ++j) {
        flo[j] = (q == 0) ? h_own[j] : h_oth[j];  // features 0..7
        fhi[j] = (q == 0) ? h_oth[j] : h_own[j];  // features 8..15
    }
    int jj0 = q * 4;
    float o0 = 0, o1 = 0, o2 = 0, o3 = 0;
#pragma unroll
    for (int kk = 0; kk < 16; ++kk) {
        float hk = (kk < 8) ? flo[kk] : fhi[kk - 8];
        const float* wr = &W2[kk * F_OUT + jj0];
        o0 = fmaf(hk, wr[0], o0);
        o1 = fmaf(hk, wr[1], o1);
        o2 = fmaf(hk, wr[2], o2);
        o3 = fmaf(hk, wr[3], o3);
    }
    *(float4*)&g2[(size_t)node * F_OUT + jj0] =
        make_float4(o0 * di, o1 * di, o2 * di, o3 * di);
}

// ---------------- layer 2 gather + bias + log_softmax, NO atomics, 8-deep MLP ----------------

__global__ __launch_bounds__(256) void k_gather2(const int* __restrict__ row_ptr,
                                                 const int* __restrict__ csr,
                                                 const float* __restrict__ dinv,
                                                 const float* __restrict__ g2,
                                                 const float* __restrict__ b2,
                                                 float* __restrict__ out, int n) {
    int t = threadIdx.x;
    int node = blockIdx.x * 128 + (t >> 1);
    int q = t & 1;
    if (node >= n) return;
    int st = row_ptr[node], en = row_ptr[node + 1];
    const float4* rows = (const float4*)g2;  // half-row q of node i at rows[i*2+q]
    float4 s4 = rows[(size_t)node * 2 + q];  // self-loop
    float a0 = s4.x, a1 = s4.y, a2 = s4.z, a3 = s4.w;
    int k = st;
    for (; k + 8 <= en; k += 8) {
        int s[8];
#pragma unroll
        for (int u = 0; u < 8; ++u) s[u] = csr[k + u];
        float4 vv[8];
#pragma unroll
        for (int u = 0; u < 8; ++u) vv[u] = rows[(size_t)s[u] * 2 + q];
#pragma unroll
        for (int u = 0; u < 8; ++u) {
            a0 += vv[u].x; a1 += vv[u].y; a2 += vv[u].z; a3 += vv[u].w;
        }
    }
    for (; k + 2 <= en; k += 2) {
        int s0 = csr[k], s1 = csr[k + 1];
        float4 v0 = rows[(size_t)s0 * 2 + q];
        float4 v1 = rows[(size_t)s1 * 2 + q];
        a0 += v0.x + v1.x; a1 += v0.y + v1.y;
        a2 += v0.z + v1.z; a3 += v0.w + v1.w;
    }
    if (k < en) {
        float4 v0 = rows[(size_t)csr[k] * 2 + q];
        a0 += v0.x; a1 += v0.y; a2 += v0.z; a3 += v0.w;
    }
    float di = dinv[node];
    float v0 = di * a0 + b2[q * 4 + 0];
    float v1 = di * a1 + b2[q * 4 + 1];
    float v2 = di * a2 + b2[q * 4 + 2];
    float v3 = di * a3 + b2[q * 4 + 3];
    float m = fmaxf(fmaxf(v0, v1), fmaxf(v2, v3));
    m = fmaxf(m, __shfl_xor(m, 1));
    float ss = expf(v0 - m) + expf(v1 - m) + expf(v2 - m) + expf(v3 - m);
    ss += __shfl_xor(ss, 1);
    float ls = m + logf(ss);
    *(float4*)&out[(size_t)node * F_OUT + q * 4] =
        make_float4(v0 - ls, v1 - ls, v2 - ls, v3 - ls);
}

// ---------------- launch ----------------

extern "C" void kernel_launch(void* const* d_in, const int* in_sizes, int n_in,
                              void* d_out, int out_size, void* d_ws, size_t ws_size,
                              hipStream_t stream) {
    const float* x  = (const float*)d_in[0];
    const int*   ei = (const int*)d_in[1];
    const float* W1 = (const float*)d_in[2];
    const float* b1 = (const float*)d_in[3];
    const float* W2 = (const float*)d_in[4];
    const float* b2 = (const float*)d_in[5];
    float* out = (float*)d_out;

    const int n = in_sizes[0] / F_IN;   // 100000
    const int e = in_sizes[1] / 2;      // 3200000
    const int* src = ei;
    const int* dst = ei + e;
    const int nb = (n + BNODES - 1) / BNODES;  // 782

    char* w = (char*)d_ws;
    float* dinv         = (float*)w; w += (size_t)n * 4;
    int* ebuf           = (int*)w;   w += (size_t)e * 4;
    int* csr            = (int*)w;   w += (size_t)e * 4;
    int* row_ptr        = (int*)w;   w += (size_t)(n + 4) * 4;
    int* bucket_cnt     = (int*)w;   w += (size_t)(nb + 4) * 4;
    int* base           = (int*)w;   w += (size_t)(nb + 4) * 4;
    int* cursor         = (int*)w;   w += (size_t)(nb + 4) * 4;
    w = (char*)(((size_t)w + 15) & ~(size_t)15);
    unsigned short* g1b = (unsigned short*)w; w += (size_t)n * F_HID * 2;
    w = (char*)(((size_t)w + 15) & ~(size_t)15);
    float* g2           = (float*)w; w += (size_t)n * F_OUT * 4;

    k_zero<<<(nb + 255) / 256, 256, 0, stream>>>(bucket_cnt, nb);
    k_hist<<<256, 256, 0, stream>>>(dst, bucket_cnt, e, nb);
    k_scan<<<1, 256, 0, stream>>>(bucket_cnt, base, cursor, row_ptr, nb, e, n);
    k_bucket<<<(e + CHUNK - 1) / CHUNK, 1024, 0, stream>>>(src, dst, cursor, ebuf, e, nb);
    k_sort<<<nb, 256, 0, stream>>>(ebuf, base, csr, row_ptr, dinv, n);
    k_gemm1<<<(n + 127) / 128, 256, 0, stream>>>(x, W1, dinv, g1b, n);
    k_gather1<<<(n + 127) / 128, 256, 0, stream>>>(row_ptr, csr, dinv, g1b, b1, W2, g2, n);
    k_gather2<<<(n + 127) / 128, 256, 0, stream>>>(row_ptr, csr, dinv, g2, b2, out, n);
}